// Round 11
// baseline (1391.935 us; speedup 1.0000x reference)
//
#include <hip/hip_runtime.h>
#include <hip/hip_cooperative_groups.h>
#include <hip/hip_bf16.h>
#include <math.h>

// 3-layer GCN on MI355X.
// R13: ONE cooperative mega-kernel. R12 analysis: kernels sum ~235us of the
//   320us total -> ~85us is 8 inter-dispatch gaps (~10us each). agg itself is
//   at its structural floor (each XCD refetches the 12.8MB hs table: 8x12.8
//   ~= the measured 90MB FETCH). So: fuse all phases into one
//   hipLaunchCooperativeKernel with grid.sync() between them (~2-3us each).
//   gemm LDS cut 34.8KB -> 17.4KB (k-split staging) so 8 blocks/CU stay
//   resident; __launch_bounds__(256,8) caps VGPR at 64; grid sized via
//   occupancy API x CU count. All phases grid-stride, no early returns.

namespace cg = cooperative_groups;

#define FDIM 64
#define BKT 128              // nodes per bucket
#define MAXNB 1024           // max buckets supported (N <= 131072)
#define BCAP 4080            // fixed edges-per-bucket region (mean 2046, sd 45)
#define TPB 256
#define ARENA_BYTES 17408    // 2 x 32 x 68 floats (gemm halves); >= partB's 8KB

typedef float f32x2 __attribute__((ext_vector_type(2)));

__device__ inline f32x2 bf2f(unsigned u) {
    f32x2 r;
    r.x = __uint_as_float(u << 16);
    r.y = __uint_as_float(u & 0xffff0000u);
    return r;
}

// ---------- phase: edge scatter into fixed per-bucket regions ----------
__device__ void partB_phase(const int* __restrict__ erow, const int* __restrict__ ecol,
                            int* __restrict__ cursor, int* __restrict__ extra,
                            unsigned* __restrict__ part,
                            int E, int NB, int nchunk, char* arena,
                            int bid, int nblk, int t) {
    int* lh = (int*)arena;
    int* lbase = lh + MAXNB;
    const int epb = (E + nchunk - 1) / nchunk;
    for (int ch = bid; ch < nchunk; ch += nblk) {
        int s = ch * epb;
        int en = s + epb; if (en > E) en = E;
        for (int i = t; i < NB; i += TPB) lh[i] = 0;
        __syncthreads();
        for (int i = s + t; i < en; i += TPB) atomicAdd(&lh[ecol[i] >> 7], 1);
        __syncthreads();
        for (int i = t; i < NB; i += TPB)
            lbase[i] = lh[i] ? atomicAdd(&cursor[i], lh[i]) : 0;
        __syncthreads();
        for (int i = t; i < NB; i += TPB) lh[i] = 0;
        __syncthreads();
        for (int i = s + t; i < en; i += TPB) {
            int c = ecol[i];
            int b = c >> 7;
            int pos = lbase[b] + atomicAdd(&lh[b], 1);
            if (pos < BCAP) part[(size_t)b * BCAP + pos] = ((unsigned)erow[i] << 7) | (unsigned)(c & 127);
            else atomicAdd(&extra[c], 1);        // overflow edge (prob ~0)
        }
        __syncthreads();                          // protect lh/lbase for next chunk
    }
}

// ---------- phase: partitioned edges -> fixed-stride adjacency + degree ----------
__device__ void adjw_phase(const unsigned* __restrict__ part, const int* __restrict__ cursor,
                           const int* __restrict__ extra, int* __restrict__ cnt,
                           int* __restrict__ adjF, int n, int NB, int cap,
                           char* arena, int bid, int nblk, int t) {
    int* lc = (int*)arena;                        // [BKT]
    for (int b = bid; b < NB; b += nblk) {
        const int v0 = b << 7;
        if (t < BKT) lc[t] = 0;
        __syncthreads();
        int tot = cursor[b];
        int s1 = (tot < BCAP) ? tot : BCAP;
        const unsigned* __restrict__ pb = part + (size_t)b * BCAP;
        for (int e = t; e < s1; e += TPB) {
            unsigned pk = pb[e];
            int c = pk & 127;
            int slot = atomicAdd(&lc[c], 1);
            if (slot < cap) adjF[(size_t)(v0 + c) * cap + slot] = (int)(pk >> 7);
        }
        __syncthreads();
        int nn = n - v0; if (nn > BKT) nn = BKT;
        if (t < nn) {
            int ex = extra[v0 + t];
            int d = lc[t] + ex;
            cnt[v0 + t] = (ex > 0) ? -d : d;      // negative = tainted -> slow path
        }
        __syncthreads();
    }
}

// ---------- phase: Hs[n,64] = bf16( rsqrt(|cnt|+1) * (X @ W) ) ----------
// 4x4 register-blocked; K split in two 32-halves so LDS = 17.4KB (8 blk/CU).
__device__ void gemm_phase(const float* __restrict__ X, const float* __restrict__ W,
                           const int* __restrict__ cnt, __hip_bfloat16* __restrict__ Hout,
                           int n, char* arena, int bid, int nblk, int t) {
    float* XT = (float*)arena;                    // [32][68] k-major
    float* Ws = (float*)arena + 32 * 68;          // [32][68]
    const int ntile = (n + 63) >> 6;
    const int tc = t & 15;
    const int tr = t >> 4;
    for (int tile = bid; tile < ntile; tile += nblk) {
        const int row0 = tile << 6;
        float acc[4][4];
        #pragma unroll
        for (int i = 0; i < 4; i++)
            #pragma unroll
            for (int j = 0; j < 4; j++) acc[i][j] = 0.0f;

        #pragma unroll
        for (int kh = 0; kh < 2; kh++) {
            __syncthreads();                      // protect prior half / prior tile
            for (int i = t; i < 2048; i += TPB) { // Ws[k][c] = W[kh*32+k][c]
                int r = i >> 6, c = i & 63;
                Ws[r * 68 + c] = W[(kh * 32 + r) * 64 + c];
            }
            for (int i = t; i < 2048; i += TPB) { // XT[k][r] = X[row0+r][kh*32+k]
                int r = i >> 5, k = i & 31;
                int gr = row0 + r;
                XT[k * 68 + r] = (gr < n) ? X[(size_t)gr * FDIM + kh * 32 + k] : 0.0f;
            }
            __syncthreads();
            #pragma unroll 8
            for (int k = 0; k < 32; k++) {
                float4 a = *(const float4*)&XT[k * 68 + 4 * tr];
                float4 b = *(const float4*)&Ws[k * 68 + 4 * tc];
                acc[0][0] += a.x * b.x; acc[0][1] += a.x * b.y; acc[0][2] += a.x * b.z; acc[0][3] += a.x * b.w;
                acc[1][0] += a.y * b.x; acc[1][1] += a.y * b.y; acc[1][2] += a.y * b.z; acc[1][3] += a.y * b.w;
                acc[2][0] += a.z * b.x; acc[2][1] += a.z * b.y; acc[2][2] += a.z * b.z; acc[2][3] += a.z * b.w;
                acc[3][0] += a.w * b.x; acc[3][1] += a.w * b.y; acc[3][2] += a.w * b.z; acc[3][3] += a.w * b.w;
            }
        }

        #pragma unroll
        for (int i = 0; i < 4; i++) {
            int gr = row0 + 4 * tr + i;
            if (gr < n) {
                float dv = rsqrtf(fabsf((float)cnt[gr]) + 1.0f);   // |cnt| + self loop
                union { ushort4 u; __hip_bfloat16 h[4]; } pk;
                pk.h[0] = __float2bfloat16(acc[i][0] * dv);
                pk.h[1] = __float2bfloat16(acc[i][1] * dv);
                pk.h[2] = __float2bfloat16(acc[i][2] * dv);
                pk.h[3] = __float2bfloat16(acc[i][3] * dv);
                *(ushort4*)&Hout[(size_t)gr * FDIM + 4 * tc] = pk.u;
            }
        }
    }
}

// ---------- phase: out[v] = dinv(v)*(hs[v] + sum_nbr hs[u]) + b (opt ELU) ----------
// 2 nodes/wave, 32 lanes/node, lane = f32x2 feature pair. No reduction.
__device__ void agg_phase(const __hip_bfloat16* __restrict__ hs, const int* __restrict__ adjF,
                          const int* __restrict__ cnt, const float* __restrict__ bias,
                          float* __restrict__ out, int n, int cap, int do_elu,
                          const int* __restrict__ erow, const int* __restrict__ ecol,
                          int etot, int bid, int nblk, int t) {
    const int ngrp = (n + 7) >> 3;
    const int lane32 = t & 31;
    const int half = (t >> 5) & 1;
    const unsigned* __restrict__ hsu = (const unsigned*)hs;
    for (int grp = bid; grp < ngrp; grp += nblk) {
        const int v = grp * 8 + (t >> 5);
        const bool alive = v < n;

        int deg_raw = alive ? cnt[v] : 0;
        int deg = (deg_raw < 0) ? -deg_raw : deg_raw;
        bool slow = alive && (deg_raw < 0 || deg > cap);

        f32x2 a = (f32x2)(0.0f);
        if (alive) a = bf2f(hsu[(size_t)v * 32 + lane32]);          // self loop

        if (alive && !slow) {                    // fast path (always, in practice)
            const int* __restrict__ av = adjF + (size_t)v * cap;
            for (int base = 0; base < deg; base += 32) {
                int mc = deg - base; if (mc > 32) mc = 32;
                int uvec = 0;
                if (lane32 < mc) uvec = av[base + lane32];           // coalesced
                int g = 0;
                for (; g + 8 <= mc; g += 8) {
                    int u0 = __shfl(uvec, g + 0, 32);
                    int u1 = __shfl(uvec, g + 1, 32);
                    int u2 = __shfl(uvec, g + 2, 32);
                    int u3 = __shfl(uvec, g + 3, 32);
                    int u4 = __shfl(uvec, g + 4, 32);
                    int u5 = __shfl(uvec, g + 5, 32);
                    int u6 = __shfl(uvec, g + 6, 32);
                    int u7 = __shfl(uvec, g + 7, 32);
                    unsigned w0 = hsu[(size_t)u0 * 32 + lane32];
                    unsigned w1 = hsu[(size_t)u1 * 32 + lane32];
                    unsigned w2 = hsu[(size_t)u2 * 32 + lane32];
                    unsigned w3 = hsu[(size_t)u3 * 32 + lane32];
                    unsigned w4 = hsu[(size_t)u4 * 32 + lane32];
                    unsigned w5 = hsu[(size_t)u5 * 32 + lane32];
                    unsigned w6 = hsu[(size_t)u6 * 32 + lane32];
                    unsigned w7 = hsu[(size_t)u7 * 32 + lane32];
                    a += bf2f(w0); a += bf2f(w1); a += bf2f(w2); a += bf2f(w3);
                    a += bf2f(w4); a += bf2f(w5); a += bf2f(w6); a += bf2f(w7);
                }
                for (; g + 4 <= mc; g += 4) {
                    int u0 = __shfl(uvec, g + 0, 32);
                    int u1 = __shfl(uvec, g + 1, 32);
                    int u2 = __shfl(uvec, g + 2, 32);
                    int u3 = __shfl(uvec, g + 3, 32);
                    unsigned w0 = hsu[(size_t)u0 * 32 + lane32];
                    unsigned w1 = hsu[(size_t)u1 * 32 + lane32];
                    unsigned w2 = hsu[(size_t)u2 * 32 + lane32];
                    unsigned w3 = hsu[(size_t)u3 * 32 + lane32];
                    a += bf2f(w0); a += bf2f(w1); a += bf2f(w2); a += bf2f(w3);
                }
                for (; g < mc; g++) {
                    int u = __shfl(uvec, g, 32);
                    a += bf2f(hsu[(size_t)u * 32 + lane32]);
                }
            }
        }
        if (__any(slow)) {
            // slow path (prob ~0): exact full-edge scan, halves vs own v
            for (int base = 0; base < etot; base += 32) {
                int m = etot - base; if (m > 32) m = 32;
                int c = -1, r = 0;
                if (lane32 < m) { c = ecol[base + lane32]; r = erow[base + lane32]; }
                unsigned long long b = __ballot(slow && (c == v));
                unsigned bh = (unsigned)(b >> (half * 32));
                while (bh) {
                    int j = __ffs(bh) - 1;
                    bh &= bh - 1;
                    int u = __shfl(r, j, 32);
                    if (slow) a += bf2f(hsu[(size_t)u * 32 + lane32]);
                }
            }
        }

        if (alive) {
            float dv = rsqrtf((float)deg + 1.0f);       // +1 self loop
            f32x2 bv = ((const f32x2*)bias)[lane32];
            f32x2 rr = a * dv + bv;
            float rx = rr.x, ry = rr.y;
            if (do_elu) {
                rx = (rx > 0.0f) ? rx : (__expf(rx) - 1.0f);
                ry = (ry > 0.0f) ? ry : (__expf(ry) - 1.0f);
            }
            ((float2*)out)[(size_t)v * 32 + lane32] = make_float2(rx, ry);
        }
    }
}

// ---------- the mega kernel ----------
__global__ __launch_bounds__(TPB, 8) void mega_kernel(
    const float* __restrict__ x,
    const int* __restrict__ erow, const int* __restrict__ ecol,
    const float* __restrict__ W1, const float* __restrict__ b1,
    const float* __restrict__ W2, const float* __restrict__ b2,
    const float* __restrict__ W3, const float* __restrict__ b3,
    __hip_bfloat16* hsb, int* cnt, int* cursor, int* extra,
    unsigned* part, int* adjF, float* outb,
    int N, int E, int NB, int cap, int nchunk) {
    cg::grid_group grid = cg::this_grid();
    __shared__ __align__(16) char arena[ARENA_BYTES];
    const int t = threadIdx.x;
    const int bid = blockIdx.x;
    const int nblk = gridDim.x;

    // phase 0: zero cursor[NB+1] + extra[N] (contiguous allocation)
    {
        int tot = NB + 1 + N;
        for (int i = bid * TPB + t; i < tot; i += nblk * TPB) cursor[i] = 0;
    }
    grid.sync();
    partB_phase(erow, ecol, cursor, extra, part, E, NB, nchunk, arena, bid, nblk, t);
    grid.sync();
    adjw_phase(part, cursor, extra, cnt, adjF, N, NB, cap, arena, bid, nblk, t);
    grid.sync();
    gemm_phase(x, W1, cnt, hsb, N, arena, bid, nblk, t);
    grid.sync();
    agg_phase(hsb, adjF, cnt, b1, outb, N, cap, 1, erow, ecol, E, bid, nblk, t);
    grid.sync();
    gemm_phase(outb, W2, cnt, hsb, N, arena, bid, nblk, t);
    grid.sync();
    agg_phase(hsb, adjF, cnt, b2, outb, N, cap, 1, erow, ecol, E, bid, nblk, t);
    grid.sync();
    gemm_phase(outb, W3, cnt, hsb, N, arena, bid, nblk, t);
    grid.sync();
    agg_phase(hsb, adjF, cnt, b3, outb, N, cap, 0, erow, ecol, E, bid, nblk, t);
}

// ---------- launch ----------

extern "C" void kernel_launch(void* const* d_in, const int* in_sizes, int n_in,
                              void* d_out, int out_size, void* d_ws, size_t ws_size,
                              hipStream_t stream) {
    const float* x   = (const float*)d_in[0];
    const int*   ei  = (const int*)d_in[1];
    const float* W1  = (const float*)d_in[2];
    const float* b1  = (const float*)d_in[3];
    const float* W2  = (const float*)d_in[4];
    const float* b2  = (const float*)d_in[5];
    const float* W3  = (const float*)d_in[6];
    const float* b3  = (const float*)d_in[7];

    const int N = in_sizes[0] / FDIM;      // 100000
    const int E = in_sizes[1] / 2;         // 1600000
    const int* erow = ei;                   // sources
    const int* ecol = ei + E;               // targets

    const int NB = (N + BKT - 1) / BKT;    // 782 buckets

    char* p = (char*)d_ws;
    __hip_bfloat16* hsb = (__hip_bfloat16*)p;  p += (size_t)N * FDIM * sizeof(__hip_bfloat16); // 12.8 MB
    int*   cnt  = (int*)p;   p += (size_t)N * sizeof(int);
    int* cursor = (int*)p;   p += (size_t)(NB + 1) * sizeof(int);   // cursor+extra contiguous
    int* extra  = (int*)p;   p += (size_t)N * sizeof(int);          // (phase-0 zero covers both)
    int*   adjF = (int*)p;

    // part[] aliases hsb: NB*BCAP*4 = 12.76MB <= N*128B = 12.8MB; dead before
    // gemm1 writes hsb (sequenced by grid.sync within the mega kernel).
    unsigned* part = (unsigned*)hsb;

    // adjacency capacity: biggest of {64,48,32} that fits the workspace
    size_t used = (size_t)(p - (char*)d_ws);
    int cap = 64;
    while (cap > 32 && used + (size_t)N * cap * sizeof(int) > ws_size) cap -= 16;

    float* outb = (float*)d_out;

    // cooperative grid: blocks/CU from the occupancy API (authoritative for
    // co-residency), x CU count. Cached after first call.
    static int gridBlocks = 0;
    if (gridBlocks == 0) {
        int bpc = 0;
        hipOccupancyMaxActiveBlocksPerMultiprocessor(&bpc, (const void*)mega_kernel, TPB, 0);
        if (bpc < 1) bpc = 1;
        if (bpc > 8) bpc = 8;
        int dev = 0;
        hipGetDevice(&dev);
        int ncu = 0;
        hipDeviceGetAttribute(&ncu, hipDeviceAttributeMultiprocessorCount, dev);
        if (ncu <= 0) ncu = 256;
        gridBlocks = bpc * ncu;
    }

    int Np = N, Ep = E, NBp = NB, capp = cap, nch = 1024;
    void* args[] = {
        (void*)&x, (void*)&erow, (void*)&ecol,
        (void*)&W1, (void*)&b1, (void*)&W2, (void*)&b2, (void*)&W3, (void*)&b3,
        (void*)&hsb, (void*)&cnt, (void*)&cursor, (void*)&extra,
        (void*)&part, (void*)&adjF, (void*)&outb,
        (void*)&Np, (void*)&Ep, (void*)&NBp, (void*)&capp, (void*)&nch
    };
    hipLaunchCooperativeKernel((const void*)mega_kernel, dim3(gridBlocks), dim3(TPB),
                               args, 0, stream);
}

// Round 13
// 974.503 us; speedup vs baseline: 1.4284x; 1.4284x over previous
//
#include <hip/hip_runtime.h>
#include <hip/hip_cooperative_groups.h>
#include <hip/hip_bf16.h>
#include <math.h>

// 3-layer GCN on MI355X.
// R14 (resubmit — prior round died on GPU acquisition, never ran):
//   R13 mega-kernel with the spill bug fixed. R13's __launch_bounds__(256,8)
//   capped VGPR at 32 -> ~200MB scratch spill traffic (WRITE 331MB vs 130
//   expected), 2200us at 3.8% VALU. Fix: (256,4) -> VGPR cap 128 (no spills),
//   cooperative grid sized by occupancy API from ACTUAL register count.
//   Also: partB chunk count = gridBlocks (R13 idled half the grid there).
//   Structure unchanged: 9 phases, grid.sync between, gemm LDS 17.4KB.

namespace cg = cooperative_groups;

#define FDIM 64
#define BKT 128              // nodes per bucket
#define MAXNB 1024           // max buckets supported (N <= 131072)
#define BCAP 4080            // fixed edges-per-bucket region (mean 2046, sd 45)
#define TPB 256
#define ARENA_BYTES 17408    // 2 x 32 x 68 floats (gemm halves); >= partB's 8KB

typedef float f32x2 __attribute__((ext_vector_type(2)));

__device__ inline f32x2 bf2f(unsigned u) {
    f32x2 r;
    r.x = __uint_as_float(u << 16);
    r.y = __uint_as_float(u & 0xffff0000u);
    return r;
}

// ---------- phase: edge scatter into fixed per-bucket regions ----------
__device__ void partB_phase(const int* __restrict__ erow, const int* __restrict__ ecol,
                            int* __restrict__ cursor, int* __restrict__ extra,
                            unsigned* __restrict__ part,
                            int E, int NB, int nchunk, char* arena,
                            int bid, int nblk, int t) {
    int* lh = (int*)arena;
    int* lbase = lh + MAXNB;
    const int epb = (E + nchunk - 1) / nchunk;
    for (int ch = bid; ch < nchunk; ch += nblk) {
        int s = ch * epb;
        int en = s + epb; if (en > E) en = E;
        for (int i = t; i < NB; i += TPB) lh[i] = 0;
        __syncthreads();
        for (int i = s + t; i < en; i += TPB) atomicAdd(&lh[ecol[i] >> 7], 1);
        __syncthreads();
        for (int i = t; i < NB; i += TPB)
            lbase[i] = lh[i] ? atomicAdd(&cursor[i], lh[i]) : 0;
        __syncthreads();
        for (int i = t; i < NB; i += TPB) lh[i] = 0;
        __syncthreads();
        for (int i = s + t; i < en; i += TPB) {
            int c = ecol[i];
            int b = c >> 7;
            int pos = lbase[b] + atomicAdd(&lh[b], 1);
            if (pos < BCAP) part[(size_t)b * BCAP + pos] = ((unsigned)erow[i] << 7) | (unsigned)(c & 127);
            else atomicAdd(&extra[c], 1);        // overflow edge (prob ~0)
        }
        __syncthreads();                          // protect lh/lbase for next chunk
    }
}

// ---------- phase: partitioned edges -> fixed-stride adjacency + degree ----------
__device__ void adjw_phase(const unsigned* __restrict__ part, const int* __restrict__ cursor,
                           const int* __restrict__ extra, int* __restrict__ cnt,
                           int* __restrict__ adjF, int n, int NB, int cap,
                           char* arena, int bid, int nblk, int t) {
    int* lc = (int*)arena;                        // [BKT]
    for (int b = bid; b < NB; b += nblk) {
        const int v0 = b << 7;
        if (t < BKT) lc[t] = 0;
        __syncthreads();
        int tot = cursor[b];
        int s1 = (tot < BCAP) ? tot : BCAP;
        const unsigned* __restrict__ pb = part + (size_t)b * BCAP;
        for (int e = t; e < s1; e += TPB) {
            unsigned pk = pb[e];
            int c = pk & 127;
            int slot = atomicAdd(&lc[c], 1);
            if (slot < cap) adjF[(size_t)(v0 + c) * cap + slot] = (int)(pk >> 7);
        }
        __syncthreads();
        int nn = n - v0; if (nn > BKT) nn = BKT;
        if (t < nn) {
            int ex = extra[v0 + t];
            int d = lc[t] + ex;
            cnt[v0 + t] = (ex > 0) ? -d : d;      // negative = tainted -> slow path
        }
        __syncthreads();
    }
}

// ---------- phase: Hs[n,64] = bf16( rsqrt(|cnt|+1) * (X @ W) ) ----------
// 4x4 register-blocked; K split in two 32-halves so LDS = 17.4KB.
__device__ void gemm_phase(const float* __restrict__ X, const float* __restrict__ W,
                           const int* __restrict__ cnt, __hip_bfloat16* __restrict__ Hout,
                           int n, char* arena, int bid, int nblk, int t) {
    float* XT = (float*)arena;                    // [32][68] k-major
    float* Ws = (float*)arena + 32 * 68;          // [32][68]
    const int ntile = (n + 63) >> 6;
    const int tc = t & 15;
    const int tr = t >> 4;
    for (int tile = bid; tile < ntile; tile += nblk) {
        const int row0 = tile << 6;
        float acc[4][4];
        #pragma unroll
        for (int i = 0; i < 4; i++)
            #pragma unroll
            for (int j = 0; j < 4; j++) acc[i][j] = 0.0f;

        #pragma unroll
        for (int kh = 0; kh < 2; kh++) {
            __syncthreads();                      // protect prior half / prior tile
            for (int i = t; i < 2048; i += TPB) { // Ws[k][c] = W[kh*32+k][c]
                int r = i >> 6, c = i & 63;
                Ws[r * 68 + c] = W[(kh * 32 + r) * 64 + c];
            }
            for (int i = t; i < 2048; i += TPB) { // XT[k][r] = X[row0+r][kh*32+k]
                int r = i >> 5, k = i & 31;
                int gr = row0 + r;
                XT[k * 68 + r] = (gr < n) ? X[(size_t)gr * FDIM + kh * 32 + k] : 0.0f;
            }
            __syncthreads();
            #pragma unroll 8
            for (int k = 0; k < 32; k++) {
                float4 a = *(const float4*)&XT[k * 68 + 4 * tr];
                float4 b = *(const float4*)&Ws[k * 68 + 4 * tc];
                acc[0][0] += a.x * b.x; acc[0][1] += a.x * b.y; acc[0][2] += a.x * b.z; acc[0][3] += a.x * b.w;
                acc[1][0] += a.y * b.x; acc[1][1] += a.y * b.y; acc[1][2] += a.y * b.z; acc[1][3] += a.y * b.w;
                acc[2][0] += a.z * b.x; acc[2][1] += a.z * b.y; acc[2][2] += a.z * b.z; acc[2][3] += a.z * b.w;
                acc[3][0] += a.w * b.x; acc[3][1] += a.w * b.y; acc[3][2] += a.w * b.z; acc[3][3] += a.w * b.w;
            }
        }

        #pragma unroll
        for (int i = 0; i < 4; i++) {
            int gr = row0 + 4 * tr + i;
            if (gr < n) {
                float dv = rsqrtf(fabsf((float)cnt[gr]) + 1.0f);   // |cnt| + self loop
                union { ushort4 u; __hip_bfloat16 h[4]; } pk;
                pk.h[0] = __float2bfloat16(acc[i][0] * dv);
                pk.h[1] = __float2bfloat16(acc[i][1] * dv);
                pk.h[2] = __float2bfloat16(acc[i][2] * dv);
                pk.h[3] = __float2bfloat16(acc[i][3] * dv);
                *(ushort4*)&Hout[(size_t)gr * FDIM + 4 * tc] = pk.u;
            }
        }
    }
}

// ---------- phase: out[v] = dinv(v)*(hs[v] + sum_nbr hs[u]) + b (opt ELU) ----------
// 2 nodes/wave, 32 lanes/node, lane = f32x2 feature pair. No reduction.
__device__ void agg_phase(const __hip_bfloat16* __restrict__ hs, const int* __restrict__ adjF,
                          const int* __restrict__ cnt, const float* __restrict__ bias,
                          float* __restrict__ out, int n, int cap, int do_elu,
                          const int* __restrict__ erow, const int* __restrict__ ecol,
                          int etot, int bid, int nblk, int t) {
    const int ngrp = (n + 7) >> 3;
    const int lane32 = t & 31;
    const int half = (t >> 5) & 1;
    const unsigned* __restrict__ hsu = (const unsigned*)hs;
    for (int grp = bid; grp < ngrp; grp += nblk) {
        const int v = grp * 8 + (t >> 5);
        const bool alive = v < n;

        int deg_raw = alive ? cnt[v] : 0;
        int deg = (deg_raw < 0) ? -deg_raw : deg_raw;
        bool slow = alive && (deg_raw < 0 || deg > cap);

        f32x2 a = (f32x2)(0.0f);
        if (alive) a = bf2f(hsu[(size_t)v * 32 + lane32]);          // self loop

        if (alive && !slow) {                    // fast path (always, in practice)
            const int* __restrict__ av = adjF + (size_t)v * cap;
            for (int base = 0; base < deg; base += 32) {
                int mc = deg - base; if (mc > 32) mc = 32;
                int uvec = 0;
                if (lane32 < mc) uvec = av[base + lane32];           // coalesced
                int g = 0;
                for (; g + 8 <= mc; g += 8) {
                    int u0 = __shfl(uvec, g + 0, 32);
                    int u1 = __shfl(uvec, g + 1, 32);
                    int u2 = __shfl(uvec, g + 2, 32);
                    int u3 = __shfl(uvec, g + 3, 32);
                    int u4 = __shfl(uvec, g + 4, 32);
                    int u5 = __shfl(uvec, g + 5, 32);
                    int u6 = __shfl(uvec, g + 6, 32);
                    int u7 = __shfl(uvec, g + 7, 32);
                    unsigned w0 = hsu[(size_t)u0 * 32 + lane32];
                    unsigned w1 = hsu[(size_t)u1 * 32 + lane32];
                    unsigned w2 = hsu[(size_t)u2 * 32 + lane32];
                    unsigned w3 = hsu[(size_t)u3 * 32 + lane32];
                    unsigned w4 = hsu[(size_t)u4 * 32 + lane32];
                    unsigned w5 = hsu[(size_t)u5 * 32 + lane32];
                    unsigned w6 = hsu[(size_t)u6 * 32 + lane32];
                    unsigned w7 = hsu[(size_t)u7 * 32 + lane32];
                    a += bf2f(w0); a += bf2f(w1); a += bf2f(w2); a += bf2f(w3);
                    a += bf2f(w4); a += bf2f(w5); a += bf2f(w6); a += bf2f(w7);
                }
                for (; g + 4 <= mc; g += 4) {
                    int u0 = __shfl(uvec, g + 0, 32);
                    int u1 = __shfl(uvec, g + 1, 32);
                    int u2 = __shfl(uvec, g + 2, 32);
                    int u3 = __shfl(uvec, g + 3, 32);
                    unsigned w0 = hsu[(size_t)u0 * 32 + lane32];
                    unsigned w1 = hsu[(size_t)u1 * 32 + lane32];
                    unsigned w2 = hsu[(size_t)u2 * 32 + lane32];
                    unsigned w3 = hsu[(size_t)u3 * 32 + lane32];
                    a += bf2f(w0); a += bf2f(w1); a += bf2f(w2); a += bf2f(w3);
                }
                for (; g < mc; g++) {
                    int u = __shfl(uvec, g, 32);
                    a += bf2f(hsu[(size_t)u * 32 + lane32]);
                }
            }
        }
        if (__any(slow)) {
            // slow path (prob ~0): exact full-edge scan, halves vs own v
            for (int base = 0; base < etot; base += 32) {
                int m = etot - base; if (m > 32) m = 32;
                int c = -1, r = 0;
                if (lane32 < m) { c = ecol[base + lane32]; r = erow[base + lane32]; }
                unsigned long long b = __ballot(slow && (c == v));
                unsigned bh = (unsigned)(b >> (half * 32));
                while (bh) {
                    int j = __ffs(bh) - 1;
                    bh &= bh - 1;
                    int u = __shfl(r, j, 32);
                    if (slow) a += bf2f(hsu[(size_t)u * 32 + lane32]);
                }
            }
        }

        if (alive) {
            float dv = rsqrtf((float)deg + 1.0f);       // +1 self loop
            f32x2 bv = ((const f32x2*)bias)[lane32];
            f32x2 rr = a * dv + bv;
            float rx = rr.x, ry = rr.y;
            if (do_elu) {
                rx = (rx > 0.0f) ? rx : (__expf(rx) - 1.0f);
                ry = (ry > 0.0f) ? ry : (__expf(ry) - 1.0f);
            }
            ((float2*)out)[(size_t)v * 32 + lane32] = make_float2(rx, ry);
        }
    }
}

// ---------- the mega kernel ----------
__global__ __launch_bounds__(TPB, 4) void mega_kernel(
    const float* __restrict__ x,
    const int* __restrict__ erow, const int* __restrict__ ecol,
    const float* __restrict__ W1, const float* __restrict__ b1,
    const float* __restrict__ W2, const float* __restrict__ b2,
    const float* __restrict__ W3, const float* __restrict__ b3,
    __hip_bfloat16* hsb, int* cnt, int* cursor, int* extra,
    unsigned* part, int* adjF, float* outb,
    int N, int E, int NB, int cap, int nchunk) {
    cg::grid_group grid = cg::this_grid();
    __shared__ __align__(16) char arena[ARENA_BYTES];
    const int t = threadIdx.x;
    const int bid = blockIdx.x;
    const int nblk = gridDim.x;

    // phase 0: zero cursor[NB+1] + extra[N] (contiguous allocation)
    {
        int tot = NB + 1 + N;
        for (int i = bid * TPB + t; i < tot; i += nblk * TPB) cursor[i] = 0;
    }
    grid.sync();
    partB_phase(erow, ecol, cursor, extra, part, E, NB, nchunk, arena, bid, nblk, t);
    grid.sync();
    adjw_phase(part, cursor, extra, cnt, adjF, N, NB, cap, arena, bid, nblk, t);
    grid.sync();
    gemm_phase(x, W1, cnt, hsb, N, arena, bid, nblk, t);
    grid.sync();
    agg_phase(hsb, adjF, cnt, b1, outb, N, cap, 1, erow, ecol, E, bid, nblk, t);
    grid.sync();
    gemm_phase(outb, W2, cnt, hsb, N, arena, bid, nblk, t);
    grid.sync();
    agg_phase(hsb, adjF, cnt, b2, outb, N, cap, 1, erow, ecol, E, bid, nblk, t);
    grid.sync();
    gemm_phase(outb, W3, cnt, hsb, N, arena, bid, nblk, t);
    grid.sync();
    agg_phase(hsb, adjF, cnt, b3, outb, N, cap, 0, erow, ecol, E, bid, nblk, t);
}

// ---------- launch ----------

extern "C" void kernel_launch(void* const* d_in, const int* in_sizes, int n_in,
                              void* d_out, int out_size, void* d_ws, size_t ws_size,
                              hipStream_t stream) {
    const float* x   = (const float*)d_in[0];
    const int*   ei  = (const int*)d_in[1];
    const float* W1  = (const float*)d_in[2];
    const float* b1  = (const float*)d_in[3];
    const float* W2  = (const float*)d_in[4];
    const float* b2  = (const float*)d_in[5];
    const float* W3  = (const float*)d_in[6];
    const float* b3  = (const float*)d_in[7];

    const int N = in_sizes[0] / FDIM;      // 100000
    const int E = in_sizes[1] / 2;         // 1600000
    const int* erow = ei;                   // sources
    const int* ecol = ei + E;               // targets

    const int NB = (N + BKT - 1) / BKT;    // 782 buckets

    char* p = (char*)d_ws;
    __hip_bfloat16* hsb = (__hip_bfloat16*)p;  p += (size_t)N * FDIM * sizeof(__hip_bfloat16); // 12.8 MB
    int*   cnt  = (int*)p;   p += (size_t)N * sizeof(int);
    int* cursor = (int*)p;   p += (size_t)(NB + 1) * sizeof(int);   // cursor+extra contiguous
    int* extra  = (int*)p;   p += (size_t)N * sizeof(int);          // (phase-0 zero covers both)
    int*   adjF = (int*)p;

    // part[] aliases hsb: NB*BCAP*4 = 12.76MB <= N*128B = 12.8MB; dead before
    // gemm1 writes hsb (sequenced by grid.sync within the mega kernel).
    unsigned* part = (unsigned*)hsb;

    // adjacency capacity: biggest of {64,48,32} that fits the workspace
    size_t used = (size_t)(p - (char*)d_ws);
    int cap = 64;
    while (cap > 32 && used + (size_t)N * cap * sizeof(int) > ws_size) cap -= 16;

    float* outb = (float*)d_out;

    // cooperative grid: blocks/CU from the occupancy API (authoritative for
    // co-residency, uses ACTUAL VGPR/LDS counts), x CU count. Cached.
    static int gridBlocks = 0;
    if (gridBlocks == 0) {
        int bpc = 0;
        hipOccupancyMaxActiveBlocksPerMultiprocessor(&bpc, (const void*)mega_kernel, TPB, 0);
        if (bpc < 1) bpc = 1;
        if (bpc > 8) bpc = 8;
        int dev = 0;
        hipGetDevice(&dev);
        int ncu = 0;
        hipDeviceGetAttribute(&ncu, hipDeviceAttributeMultiprocessorCount, dev);
        if (ncu <= 0) ncu = 256;
        gridBlocks = bpc * ncu;
    }

    int Np = N, Ep = E, NBp = NB, capp = cap, nch = gridBlocks;
    void* args[] = {
        (void*)&x, (void*)&erow, (void*)&ecol,
        (void*)&W1, (void*)&b1, (void*)&W2, (void*)&b2, (void*)&W3, (void*)&b3,
        (void*)&hsb, (void*)&cnt, (void*)&cursor, (void*)&extra,
        (void*)&part, (void*)&adjF, (void*)&outb,
        (void*)&Np, (void*)&Ep, (void*)&NBp, (void*)&capp, (void*)&nch
    };
    hipLaunchCooperativeKernel((const void*)mega_kernel, dim3(gridBlocks), dim3(TPB),
                               args, 0, stream);
}

// Round 15
// 295.393 us; speedup vs baseline: 4.7122x; 3.2990x over previous
//
#include <hip/hip_runtime.h>
#include <hip/hip_bf16.h>
#include <math.h>

// 3-layer GCN on MI355X.
// R15 (resubmit — prior round died on GPU acquisition, never ran):
//   cooperative mega-kernel abandoned (R14: 1274us, grid.sync+49% occ >>
//   the 8x11us gaps it saved). Back to split dispatches, but with BLOCK-LOCAL
//   merges at full occupancy (<=17.4KB LDS -> 8 blocks/CU; R10's fusion fail
//   was 33.8KB -> 32% occ, consistent with 47us x 68/32 ~= its 99us):
//   - adjw+gemm1: bucket b = 2 gemm tiles; cnt stays in LDS between phases.
//   - aggL+gemm(L+1) x2: agg writes h into LDS XT (h's only consumer);
//     gemm reads W from global (L1 broadcast) so LDS stays 17.4KB.
//   - agg3 standalone. 9 -> 6 dispatches; h1/h2/X never round-trip HBM.
//   part[] de-aliased from hsb (required by adjw+gemm1 merge; ws is 256MB).

#define FDIM 64
#define BKT 128              // nodes per bucket
#define MAXNB 1024           // max buckets supported (N <= 131072)
#define BCAP 4080            // fixed edges-per-bucket region (mean 2046, sd 45)

typedef float f32x2 __attribute__((ext_vector_type(2)));

__device__ inline f32x2 bf2f(unsigned u) {
    f32x2 r;
    r.x = __uint_as_float(u << 16);
    r.y = __uint_as_float(u & 0xffff0000u);
    return r;
}

// ---------- build: scatter edges into fixed per-bucket regions ----------
__global__ __launch_bounds__(1024) void partB_kernel(const int* __restrict__ erow,
                                                     const int* __restrict__ ecol,
                                                     int* __restrict__ cursor,
                                                     int* __restrict__ extra,
                                                     unsigned* __restrict__ part,
                                                     int e, int nb, int epb) {
    __shared__ int lh[MAXNB];
    __shared__ int lbase[MAXNB];
    const int t = threadIdx.x;
    for (int i = t; i < nb; i += 1024) lh[i] = 0;
    __syncthreads();
    int s = blockIdx.x * epb;
    int en = s + epb; if (en > e) en = e;
    for (int i = s + t; i < en; i += 1024) atomicAdd(&lh[ecol[i] >> 7], 1);
    __syncthreads();
    for (int i = t; i < nb; i += 1024)
        lbase[i] = lh[i] ? atomicAdd(&cursor[i], lh[i]) : 0;
    __syncthreads();
    for (int i = t; i < nb; i += 1024) lh[i] = 0;
    __syncthreads();
    for (int i = s + t; i < en; i += 1024) {
        int c = ecol[i];
        int b = c >> 7;
        int pos = lbase[b] + atomicAdd(&lh[b], 1);
        if (pos < BCAP) part[(size_t)b * BCAP + pos] = ((unsigned)erow[i] << 7) | (unsigned)(c & 127);
        else atomicAdd(&extra[c], 1);            // overflow edge (prob ~0)
    }
}

// ---------- adjw + gemm1 (block per bucket = 128 nodes = 2 gemm tiles) ----------
// Phase A: part -> adjF + signed cnt (LDS + global).
// Phase B: Hs[v] = bf16( rsqrt(|cnt|+1) * (X[v] @ W1) ) for the bucket's rows,
//          k-split staging (17.4KB arena), dv from LDS scnt.
__global__ __launch_bounds__(256, 4) void adjw_gemm1_kernel(
        const unsigned* __restrict__ part, const int* __restrict__ cursor,
        const int* __restrict__ extra, const float* __restrict__ X,
        const float* __restrict__ W, int* __restrict__ cnt,
        int* __restrict__ adjF, __hip_bfloat16* __restrict__ Hout,
        int n, int cap) {
    __shared__ int scnt[BKT];
    __shared__ float arena[2 * 32 * 68];          // XT[32][68] + Ws[32][68]
    const int b = blockIdx.x;
    const int t = threadIdx.x;
    const int v0 = b << 7;

    // --- phase A: adjacency write + degree ---
    if (t < BKT) scnt[t] = 0;
    __syncthreads();
    int tot = cursor[b];
    int s1 = (tot < BCAP) ? tot : BCAP;
    const unsigned* __restrict__ pb = part + (size_t)b * BCAP;
    for (int e = t; e < s1; e += 256) {
        unsigned pk = pb[e];
        int c = pk & 127;
        int slot = atomicAdd(&scnt[c], 1);
        if (slot < cap) adjF[(size_t)(v0 + c) * cap + slot] = (int)(pk >> 7);
    }
    __syncthreads();
    int nn = n - v0; if (nn > BKT) nn = BKT; if (nn < 0) nn = 0;
    if (t < nn) {
        int ex = extra[v0 + t];
        int d = scnt[t] + ex;
        int sv = (ex > 0) ? -d : d;               // negative = tainted -> slow path
        cnt[v0 + t] = sv;
        scnt[t] = sv;                             // signed copy for phase B
    }
    __syncthreads();

    // --- phase B: gemm over the bucket's two 64-row tiles ---
    float* XT = arena;                            // [32][68] k-major
    float* Ws = arena + 32 * 68;                  // [32][68]
    const int tc = t & 15;
    const int tr = t >> 4;
    for (int sub = 0; sub < 2; ++sub) {
        const int row0 = v0 + (sub << 6);
        float acc[4][4];
        #pragma unroll
        for (int i = 0; i < 4; i++)
            #pragma unroll
            for (int j = 0; j < 4; j++) acc[i][j] = 0.0f;

        #pragma unroll
        for (int kh = 0; kh < 2; kh++) {
            __syncthreads();
            for (int i = t; i < 2048; i += 256) {
                int r = i >> 6, c = i & 63;
                Ws[r * 68 + c] = W[(kh * 32 + r) * 64 + c];
            }
            for (int i = t; i < 2048; i += 256) {
                int r = i >> 5, k = i & 31;
                int gr = row0 + r;
                XT[k * 68 + r] = (gr < n) ? X[(size_t)gr * FDIM + kh * 32 + k] : 0.0f;
            }
            __syncthreads();
            #pragma unroll 8
            for (int k = 0; k < 32; k++) {
                float4 a = *(const float4*)&XT[k * 68 + 4 * tr];
                float4 bb = *(const float4*)&Ws[k * 68 + 4 * tc];
                acc[0][0] += a.x * bb.x; acc[0][1] += a.x * bb.y; acc[0][2] += a.x * bb.z; acc[0][3] += a.x * bb.w;
                acc[1][0] += a.y * bb.x; acc[1][1] += a.y * bb.y; acc[1][2] += a.y * bb.z; acc[1][3] += a.y * bb.w;
                acc[2][0] += a.z * bb.x; acc[2][1] += a.z * bb.y; acc[2][2] += a.z * bb.z; acc[2][3] += a.z * bb.w;
                acc[3][0] += a.w * bb.x; acc[3][1] += a.w * bb.y; acc[3][2] += a.w * bb.z; acc[3][3] += a.w * bb.w;
            }
        }

        #pragma unroll
        for (int i = 0; i < 4; i++) {
            int gr = row0 + 4 * tr + i;
            if (gr < n) {
                int sc = scnt[(sub << 6) + 4 * tr + i];
                float dv = rsqrtf(fabsf((float)sc) + 1.0f);        // |cnt| + self loop
                union { ushort4 u; __hip_bfloat16 h[4]; } pk;
                pk.h[0] = __float2bfloat16(acc[i][0] * dv);
                pk.h[1] = __float2bfloat16(acc[i][1] * dv);
                pk.h[2] = __float2bfloat16(acc[i][2] * dv);
                pk.h[3] = __float2bfloat16(acc[i][3] * dv);
                *(ushort4*)&Hout[(size_t)gr * FDIM + 4 * tc] = pk.u;
            }
        }
    }
}

// ---------- fused middle layer: agg(hs_in)+bias+ELU -> LDS XT -> @Wn -> hs_out ----------
// Block = 64-node tile. agg: 2 nodes/wave (lane=f32x2 pair), 8 passes.
// gemm: XT from LDS, W from GLOBAL (L1 broadcast) -> LDS stays 17.4KB (8 blk/CU).
__global__ __launch_bounds__(256, 4) void fused_kernel(
        const __hip_bfloat16* __restrict__ hs_in, const int* __restrict__ adjF,
        const int* __restrict__ cnt, const float* __restrict__ bias,
        const float* __restrict__ Wn, __hip_bfloat16* __restrict__ hs_out,
        int n, int cap, const int* __restrict__ erow,
        const int* __restrict__ ecol, int etot) {
    __shared__ float XT[64 * 68];                 // [feat][node_local], 17408 B
    const int t = threadIdx.x;
    const int row0 = blockIdx.x << 6;
    const int lane32 = t & 31;
    const int half = (t >> 5) & 1;
    const unsigned* __restrict__ hsu = (const unsigned*)hs_in;

    // --- agg phase: 8 passes x 8 nodes (4 waves x 2 nodes) ---
    for (int pass = 0; pass < 8; ++pass) {
        const int c = pass * 8 + (t >> 5);
        const int v = row0 + c;
        const bool alive = v < n;
        int deg_raw = alive ? cnt[v] : 0;
        int deg = (deg_raw < 0) ? -deg_raw : deg_raw;
        bool slow = alive && (deg_raw < 0 || deg > cap);

        f32x2 a = (f32x2)(0.0f);
        if (alive) a = bf2f(hsu[(size_t)v * 32 + lane32]);          // self loop

        if (alive && !slow) {
            const int* __restrict__ av = adjF + (size_t)v * cap;
            for (int base = 0; base < deg; base += 32) {
                int mc = deg - base; if (mc > 32) mc = 32;
                int uvec = 0;
                if (lane32 < mc) uvec = av[base + lane32];           // coalesced
                int g = 0;
                for (; g + 8 <= mc; g += 8) {
                    int u0 = __shfl(uvec, g + 0, 32);
                    int u1 = __shfl(uvec, g + 1, 32);
                    int u2 = __shfl(uvec, g + 2, 32);
                    int u3 = __shfl(uvec, g + 3, 32);
                    int u4 = __shfl(uvec, g + 4, 32);
                    int u5 = __shfl(uvec, g + 5, 32);
                    int u6 = __shfl(uvec, g + 6, 32);
                    int u7 = __shfl(uvec, g + 7, 32);
                    unsigned w0 = hsu[(size_t)u0 * 32 + lane32];
                    unsigned w1 = hsu[(size_t)u1 * 32 + lane32];
                    unsigned w2 = hsu[(size_t)u2 * 32 + lane32];
                    unsigned w3 = hsu[(size_t)u3 * 32 + lane32];
                    unsigned w4 = hsu[(size_t)u4 * 32 + lane32];
                    unsigned w5 = hsu[(size_t)u5 * 32 + lane32];
                    unsigned w6 = hsu[(size_t)u6 * 32 + lane32];
                    unsigned w7 = hsu[(size_t)u7 * 32 + lane32];
                    a += bf2f(w0); a += bf2f(w1); a += bf2f(w2); a += bf2f(w3);
                    a += bf2f(w4); a += bf2f(w5); a += bf2f(w6); a += bf2f(w7);
                }
                for (; g + 4 <= mc; g += 4) {
                    int u0 = __shfl(uvec, g + 0, 32);
                    int u1 = __shfl(uvec, g + 1, 32);
                    int u2 = __shfl(uvec, g + 2, 32);
                    int u3 = __shfl(uvec, g + 3, 32);
                    unsigned w0 = hsu[(size_t)u0 * 32 + lane32];
                    unsigned w1 = hsu[(size_t)u1 * 32 + lane32];
                    unsigned w2 = hsu[(size_t)u2 * 32 + lane32];
                    unsigned w3 = hsu[(size_t)u3 * 32 + lane32];
                    a += bf2f(w0); a += bf2f(w1); a += bf2f(w2); a += bf2f(w3);
                }
                for (; g < mc; g++) {
                    int u = __shfl(uvec, g, 32);
                    a += bf2f(hsu[(size_t)u * 32 + lane32]);
                }
            }
        }
        if (__any(slow)) {
            for (int base = 0; base < etot; base += 32) {
                int m = etot - base; if (m > 32) m = 32;
                int cc = -1, r = 0;
                if (lane32 < m) { cc = ecol[base + lane32]; r = erow[base + lane32]; }
                unsigned long long bl = __ballot(slow && (cc == v));
                unsigned bh = (unsigned)(bl >> (half * 32));
                while (bh) {
                    int j = __ffs(bh) - 1;
                    bh &= bh - 1;
                    int u = __shfl(r, j, 32);
                    if (slow) a += bf2f(hsu[(size_t)u * 32 + lane32]);
                }
            }
        }

        float dv = rsqrtf((float)deg + 1.0f);       // +1 self loop
        f32x2 bv = ((const f32x2*)bias)[lane32];
        f32x2 rr = a * dv + bv;
        float rx = rr.x, ry = rr.y;
        rx = (rx > 0.0f) ? rx : (__expf(rx) - 1.0f);   // ELU (middle layers always)
        ry = (ry > 0.0f) ? ry : (__expf(ry) - 1.0f);
        if (!alive) { rx = 0.0f; ry = 0.0f; }
        XT[(2 * lane32) * 68 + c] = rx;
        XT[(2 * lane32 + 1) * 68 + c] = ry;
    }
    __syncthreads();

    // --- gemm phase: hs_out = bf16( dinv * (XT^T @ Wn) ), W from global ---
    const int tc = t & 15;
    const int tr = t >> 4;
    float acc[4][4];
    #pragma unroll
    for (int i = 0; i < 4; i++)
        #pragma unroll
        for (int j = 0; j < 4; j++) acc[i][j] = 0.0f;

    const float4* __restrict__ W4 = (const float4*)Wn;
    #pragma unroll 8
    for (int k = 0; k < 64; k++) {
        float4 a = *(const float4*)&XT[k * 68 + 4 * tr];
        float4 bb = W4[k * 16 + tc];
        acc[0][0] += a.x * bb.x; acc[0][1] += a.x * bb.y; acc[0][2] += a.x * bb.z; acc[0][3] += a.x * bb.w;
        acc[1][0] += a.y * bb.x; acc[1][1] += a.y * bb.y; acc[1][2] += a.y * bb.z; acc[1][3] += a.y * bb.w;
        acc[2][0] += a.z * bb.x; acc[2][1] += a.z * bb.y; acc[2][2] += a.z * bb.z; acc[2][3] += a.z * bb.w;
        acc[3][0] += a.w * bb.x; acc[3][1] += a.w * bb.y; acc[3][2] += a.w * bb.z; acc[3][3] += a.w * bb.w;
    }

    #pragma unroll
    for (int i = 0; i < 4; i++) {
        int gr = row0 + 4 * tr + i;
        if (gr < n) {
            float dv = rsqrtf(fabsf((float)cnt[gr]) + 1.0f);
            union { ushort4 u; __hip_bfloat16 h[4]; } pk;
            pk.h[0] = __float2bfloat16(acc[i][0] * dv);
            pk.h[1] = __float2bfloat16(acc[i][1] * dv);
            pk.h[2] = __float2bfloat16(acc[i][2] * dv);
            pk.h[3] = __float2bfloat16(acc[i][3] * dv);
            *(ushort4*)&hs_out[(size_t)gr * FDIM + 4 * tc] = pk.u;
        }
    }
}

// ---------- final layer: agg + bias (no ELU) -> fp32 out ----------
__global__ __launch_bounds__(256) void agg_kernel(const __hip_bfloat16* __restrict__ hs,
                                                  const int* __restrict__ adjF,
                                                  const int* __restrict__ cnt,
                                                  const float* __restrict__ bias,
                                                  float* __restrict__ out,
                                                  int n, int cap,
                                                  const int* __restrict__ erow,
                                                  const int* __restrict__ ecol, int etot) {
    const int tid = threadIdx.x;
    const int v = blockIdx.x * 8 + (tid >> 5);
    const int lane32 = tid & 31;
    const int half = (tid >> 5) & 1;
    const bool alive = v < n;
    const unsigned* __restrict__ hsu = (const unsigned*)hs;

    int deg_raw = alive ? cnt[v] : 0;
    int deg = (deg_raw < 0) ? -deg_raw : deg_raw;
    bool slow = alive && (deg_raw < 0 || deg > cap);

    f32x2 a = (f32x2)(0.0f);
    if (alive) a = bf2f(hsu[(size_t)v * 32 + lane32]);          // self loop

    if (alive && !slow) {
        const int* __restrict__ av = adjF + (size_t)v * cap;
        for (int base = 0; base < deg; base += 32) {
            int mc = deg - base; if (mc > 32) mc = 32;
            int uvec = 0;
            if (lane32 < mc) uvec = av[base + lane32];           // coalesced
            int g = 0;
            for (; g + 8 <= mc; g += 8) {
                int u0 = __shfl(uvec, g + 0, 32);
                int u1 = __shfl(uvec, g + 1, 32);
                int u2 = __shfl(uvec, g + 2, 32);
                int u3 = __shfl(uvec, g + 3, 32);
                int u4 = __shfl(uvec, g + 4, 32);
                int u5 = __shfl(uvec, g + 5, 32);
                int u6 = __shfl(uvec, g + 6, 32);
                int u7 = __shfl(uvec, g + 7, 32);
                unsigned w0 = hsu[(size_t)u0 * 32 + lane32];
                unsigned w1 = hsu[(size_t)u1 * 32 + lane32];
                unsigned w2 = hsu[(size_t)u2 * 32 + lane32];
                unsigned w3 = hsu[(size_t)u3 * 32 + lane32];
                unsigned w4 = hsu[(size_t)u4 * 32 + lane32];
                unsigned w5 = hsu[(size_t)u5 * 32 + lane32];
                unsigned w6 = hsu[(size_t)u6 * 32 + lane32];
                unsigned w7 = hsu[(size_t)u7 * 32 + lane32];
                a += bf2f(w0); a += bf2f(w1); a += bf2f(w2); a += bf2f(w3);
                a += bf2f(w4); a += bf2f(w5); a += bf2f(w6); a += bf2f(w7);
            }
            for (; g + 4 <= mc; g += 4) {
                int u0 = __shfl(uvec, g + 0, 32);
                int u1 = __shfl(uvec, g + 1, 32);
                int u2 = __shfl(uvec, g + 2, 32);
                int u3 = __shfl(uvec, g + 3, 32);
                unsigned w0 = hsu[(size_t)u0 * 32 + lane32];
                unsigned w1 = hsu[(size_t)u1 * 32 + lane32];
                unsigned w2 = hsu[(size_t)u2 * 32 + lane32];
                unsigned w3 = hsu[(size_t)u3 * 32 + lane32];
                a += bf2f(w0); a += bf2f(w1); a += bf2f(w2); a += bf2f(w3);
            }
            for (; g < mc; g++) {
                int u = __shfl(uvec, g, 32);
                a += bf2f(hsu[(size_t)u * 32 + lane32]);
            }
        }
    }
    if (__any(slow)) {
        for (int base = 0; base < etot; base += 32) {
            int m = etot - base; if (m > 32) m = 32;
            int c = -1, r = 0;
            if (lane32 < m) { c = ecol[base + lane32]; r = erow[base + lane32]; }
            unsigned long long b = __ballot(slow && (c == v));
            unsigned bh = (unsigned)(b >> (half * 32));
            while (bh) {
                int j = __ffs(bh) - 1;
                bh &= bh - 1;
                int u = __shfl(r, j, 32);
                if (slow) a += bf2f(hsu[(size_t)u * 32 + lane32]);
            }
        }
    }

    if (alive) {
        float dv = rsqrtf((float)deg + 1.0f);       // +1 self loop
        f32x2 bv = ((const f32x2*)bias)[lane32];
        f32x2 rr = a * dv + bv;
        ((float2*)out)[(size_t)v * 32 + lane32] = make_float2(rr.x, rr.y);
    }
}

// ---------- launch ----------

extern "C" void kernel_launch(void* const* d_in, const int* in_sizes, int n_in,
                              void* d_out, int out_size, void* d_ws, size_t ws_size,
                              hipStream_t stream) {
    const float* x   = (const float*)d_in[0];
    const int*   ei  = (const int*)d_in[1];
    const float* W1  = (const float*)d_in[2];
    const float* b1  = (const float*)d_in[3];
    const float* W2  = (const float*)d_in[4];
    const float* b2  = (const float*)d_in[5];
    const float* W3  = (const float*)d_in[6];
    const float* b3  = (const float*)d_in[7];

    const int N = in_sizes[0] / FDIM;      // 100000
    const int E = in_sizes[1] / 2;         // 1600000
    const int* erow = ei;                   // sources
    const int* ecol = ei + E;               // targets

    const int NB = (N + BKT - 1) / BKT;    // 782 buckets

    char* p = (char*)d_ws;
    __hip_bfloat16* hsbA = (__hip_bfloat16*)p;  p += (size_t)N * FDIM * sizeof(__hip_bfloat16); // 12.8 MB
    __hip_bfloat16* hsbB = (__hip_bfloat16*)p;  p += (size_t)N * FDIM * sizeof(__hip_bfloat16); // 12.8 MB
    int*   cnt  = (int*)p;   p += (size_t)N * sizeof(int);
    int* cursor = (int*)p;   p += (size_t)(NB + 1) * sizeof(int);   // cursor+extra contiguous
    int* extra  = (int*)p;   p += (size_t)N * sizeof(int);          // (one memset covers both)
    unsigned* part = (unsigned*)p; p += (size_t)NB * BCAP * sizeof(unsigned);  // 12.76 MB, NOT aliased
    int*   adjF = (int*)p;

    // adjacency capacity: biggest of {64,48,32} that fits the workspace
    size_t used = (size_t)(p - (char*)d_ws);
    int cap = 64;
    while (cap > 32 && used + (size_t)N * cap * sizeof(int) > ws_size) cap -= 16;

    float* outb = (float*)d_out;

    const int TB = 256;
    const int PBLK = 256;                        // partition blocks (1024 thr each)
    const int epb = (E + PBLK - 1) / PBLK;       // edges per partition block
    const int ntile = (N + 63) / 64;             // 1563 fused tiles
    const int nblkA = (N + 7) / 8;               // agg3 blocks

    hipMemsetAsync(cursor, 0, (size_t)(NB + 1 + N) * sizeof(int), stream);
    partB_kernel<<<PBLK, 1024, 0, stream>>>(erow, ecol, cursor, extra, part, E, NB, epb);
    adjw_gemm1_kernel<<<NB, TB, 0, stream>>>(part, cursor, extra, x, W1, cnt, adjF, hsbA, N, cap);
    fused_kernel<<<ntile, TB, 0, stream>>>(hsbA, adjF, cnt, b1, W2, hsbB, N, cap, erow, ecol, E);
    fused_kernel<<<ntile, TB, 0, stream>>>(hsbB, adjF, cnt, b2, W3, hsbA, N, cap, erow, ecol, E);
    agg_kernel<<<nblkA, TB, 0, stream>>>(hsbA, adjF, cnt, b3, outb, N, cap, erow, ecol, E);
}